// Round 1
// baseline (2965.574 us; speedup 1.0000x reference)
//
#include <hip/hip_runtime.h>

typedef unsigned short u16;
typedef unsigned int   u32;
typedef short bf16x8 __attribute__((ext_vector_type(8)));
typedef float f32x4  __attribute__((ext_vector_type(4)));

#define SQ 2048            // sequence length
#define DMODEL 2048        // embed dim
#define NROWS 4096         // b*s
#define LAMBDA_INIT 0.7836057665316245f
#define OUT_SCALE   0.21639423346837552f   // 1 - LAMBDA_INIT

// ---------- helpers ----------
__device__ __forceinline__ float bf2f(u16 u) {
    union { u32 u; float f; } x; x.u = ((u32)u) << 16; return x.f;
}
__device__ __forceinline__ u16 f2bf(float f) {
    union { float f; u32 u; } x; x.f = f;
    u32 r = x.u + 0x7fffu + ((x.u >> 16) & 1u);   // RNE
    return (u16)(r >> 16);
}
__device__ __forceinline__ void cvt8(uint4 v, float4& a, float4& b) {
    a.x = bf2f((u16)(v.x & 0xffff)); a.y = bf2f((u16)(v.x >> 16));
    a.z = bf2f((u16)(v.y & 0xffff)); a.w = bf2f((u16)(v.y >> 16));
    b.x = bf2f((u16)(v.z & 0xffff)); b.y = bf2f((u16)(v.z >> 16));
    b.z = bf2f((u16)(v.w & 0xffff)); b.w = bf2f((u16)(v.w >> 16));
}

// ---------- W transpose + bf16 convert: Wt[n][k] = bf16(W[k][n]) ----------
__global__ __launch_bounds__(256) void transpose_w(const float* __restrict__ W0,
                                                   const float* __restrict__ W1,
                                                   const float* __restrict__ W2,
                                                   const float* __restrict__ W3,
                                                   u16* __restrict__ out) {
    __shared__ float tile[32][33];
    const int z = blockIdx.z;
    const float* W = (z == 0) ? W0 : (z == 1) ? W1 : (z == 2) ? W2 : W3;
    u16* O = out + (size_t)z * DMODEL * DMODEL;
    const int tx = threadIdx.x, ty = threadIdx.y;
    const int bx = blockIdx.x, by = blockIdx.y;
#pragma unroll
    for (int j = 0; j < 4; ++j)
        tile[ty + j * 8][tx] = W[(size_t)(by * 32 + ty + j * 8) * DMODEL + bx * 32 + tx];
    __syncthreads();
#pragma unroll
    for (int j = 0; j < 4; ++j)
        O[(size_t)(bx * 32 + ty + j * 8) * DMODEL + by * 32 + tx] = f2bf(tile[tx][ty + j * 8]);
}

// ---------- x -> bf16 ----------
__global__ __launch_bounds__(256) void cvt_x(const float* __restrict__ x, u16* __restrict__ xb) {
    const size_t i = ((size_t)blockIdx.x * 256 + threadIdx.x) * 8;
    float4 a = *(const float4*)(x + i);
    float4 b = *(const float4*)(x + i + 4);
    uint4 o;
    o.x = (u32)f2bf(a.x) | ((u32)f2bf(a.y) << 16);
    o.y = (u32)f2bf(a.z) | ((u32)f2bf(a.w) << 16);
    o.z = (u32)f2bf(b.x) | ((u32)f2bf(b.y) << 16);
    o.w = (u32)f2bf(b.z) | ((u32)f2bf(b.w) << 16);
    *(uint4*)(xb + i) = o;
}

// ---------- MFMA GEMM: C = A(MxK) x Bt(NxK)^T ; M=4096,N=2048,K=2048 ----------
// 128x128 tile, BK=32, 4 waves (2x2), each wave 64x64 = 4x4 MFMAs of 16x16x32.
template <bool OUT_BF16>
__global__ __launch_bounds__(256) void gemm_bt(const u16* __restrict__ A,
                                               const u16* __restrict__ Bt0,
                                               void* __restrict__ C0) {
    __shared__ u16 As[128 * 40];   // pad row stride 40 bf16 (stride 20 words == 4 mod 8: conflict-free-ish)
    __shared__ u16 Bs[128 * 40];
    const int tid  = threadIdx.x;
    const int lane = tid & 63, wave = tid >> 6;
    const int wm = wave & 1, wn = wave >> 1;
    const int l15 = lane & 15, quad = lane >> 4;
    const int tm = blockIdx.y * 128, tn = blockIdx.x * 128;
    const u16* Bt = Bt0 + (size_t)blockIdx.z * DMODEL * DMODEL;

    f32x4 acc[4][4] = {};

    for (int k0 = 0; k0 < DMODEL; k0 += 32) {
#pragma unroll
        for (int p = 0; p < 2; ++p) {
            const int slot = p * 256 + tid;
            const int r = slot >> 2, cg = slot & 3;
            const uint4 va = *(const uint4*)(A  + (size_t)(tm + r) * DMODEL + k0 + cg * 8);
            *(uint4*)(As + r * 40 + cg * 8) = va;
            const uint4 vb = *(const uint4*)(Bt + (size_t)(tn + r) * DMODEL + k0 + cg * 8);
            *(uint4*)(Bs + r * 40 + cg * 8) = vb;
        }
        __syncthreads();
        bf16x8 af[4], bfr[4];
#pragma unroll
        for (int mb = 0; mb < 4; ++mb)
            af[mb] = *(const bf16x8*)(As + (wm * 64 + mb * 16 + l15) * 40 + quad * 8);
#pragma unroll
        for (int nb = 0; nb < 4; ++nb)
            bfr[nb] = *(const bf16x8*)(Bs + (wn * 64 + nb * 16 + l15) * 40 + quad * 8);
#pragma unroll
        for (int mb = 0; mb < 4; ++mb)
#pragma unroll
            for (int nb = 0; nb < 4; ++nb)
                acc[mb][nb] = __builtin_amdgcn_mfma_f32_16x16x32_bf16(af[mb], bfr[nb], acc[mb][nb], 0, 0, 0);
        __syncthreads();
    }
    // epilogue: C/D layout col=lane&15, row=quad*4+r
#pragma unroll
    for (int mb = 0; mb < 4; ++mb)
#pragma unroll
        for (int nb = 0; nb < 4; ++nb)
#pragma unroll
            for (int r = 0; r < 4; ++r) {
                const int row = tm + wm * 64 + mb * 16 + quad * 4 + r;
                const int col = tn + wn * 64 + nb * 16 + l15;
                const float v = acc[mb][nb][r];
                if (OUT_BF16) {
                    u16* C = (u16*)C0 + (size_t)blockIdx.z * NROWS * DMODEL;
                    C[(size_t)row * DMODEL + col] = f2bf(v);
                } else {
                    float* C = (float*)C0;
                    C[(size_t)row * DMODEL + col] = v;
                }
            }
}

// ---------- RoPE in place on bf16 q or k: [4096][2048] = [row][32 heads x 64] ----------
__global__ __launch_bounds__(256) void rope_kernel(u16* __restrict__ qw, u16* __restrict__ kw) {
    const int row = blockIdx.x;
    const int spos = row & (SQ - 1);
    u16* buf = blockIdx.y ? kw : qw;
    for (int idx = threadIdx.x; idx < 1024; idx += 256) {
        const int h2 = idx >> 5, i = idx & 31;
        const size_t base = (size_t)row * DMODEL + h2 * 64 + 2 * i;
        const float x1 = bf2f(buf[base]), x2 = bf2f(buf[base + 1]);
        // inv_freq = 10000^(-i/32) = exp2(-i * log2(10000)/32)
        const float f = (float)spos * exp2f(-0.41524101186092034f * (float)i);
        const float c = cosf(f), sn = sinf(f);
        buf[base]     = f2bf(x1 * c - x2 * sn);
        buf[base + 1] = f2bf(x2 * c + x1 * sn);
    }
}

// ---------- lambda scalar ----------
__global__ void lam_kernel(const float* __restrict__ lq1, const float* __restrict__ lk1,
                           const float* __restrict__ lq2, const float* __restrict__ lk2,
                           float* __restrict__ out) {
    const int l = threadIdx.x;  // 64
    float v1 = lq1[l] * lk1[l];
    float v2 = lq2[l] * lk2[l];
#pragma unroll
    for (int off = 32; off; off >>= 1) {
        v1 += __shfl_xor(v1, off);
        v2 += __shfl_xor(v2, off);
    }
    if (l == 0) out[0] = __expf(v1) - __expf(v2) + LAMBDA_INIT;
}

// ---------- scalar flash attention ----------
// grid (SQ/32, 32): block handles (b,h, 32 q rows). 4 waves x 8 rows.
// lane: which = lane>>5 (0 -> q1k1, 1 -> q2k2), j = lane&31 (key in tile of 32).
#define QB 32
#define KBT 32
__global__ __launch_bounds__(256) void attn_kernel(const u16* __restrict__ qw,
                                                   const u16* __restrict__ kw,
                                                   const u16* __restrict__ vw,
                                                   float* __restrict__ attn1,
                                                   float* __restrict__ attn2) {
    __shared__ float Qs[QB][132];    // [row][0..63 = q1, 64..127 = q2]
    __shared__ float Ks[KBT][132];   // [key][0..63 = k1, 64..127 = k2]
    __shared__ float Vs[KBT][132];   // [key][128 v dims]
    __shared__ float Ps[4][2][KBT];

    const int tid = threadIdx.x, lane = tid & 63, wave = tid >> 6;
    const int which = lane >> 5, j = lane & 31;
    const int q0 = blockIdx.x * QB;
    const int b = blockIdx.y >> 4, h = blockIdx.y & 15;
    const size_t rowbase = (size_t)b * SQ;
    const int coff = h * 128;

    // stage Q (32 rows x 16 segs of 8 bf16)
    for (int slot = tid; slot < QB * 16; slot += 256) {
        const int r = slot >> 4, seg = slot & 15;
        uint4 v = *(const uint4*)(qw + (rowbase + q0 + r) * DMODEL + coff + seg * 8);
        float4 a, c; cvt8(v, a, c);
        *(float4*)&Qs[r][seg * 8] = a;
        *(float4*)&Qs[r][seg * 8 + 4] = c;
    }

    float o00[8], o01[8], o10[8], o11[8], m_[8], l_[8];
#pragma unroll
    for (int r8 = 0; r8 < 8; ++r8) {
        o00[r8] = o01[r8] = o10[r8] = o11[r8] = 0.f;
        m_[r8] = -1e30f; l_[r8] = 0.f;
    }

    const int ntiles = (q0 + QB - 1) / KBT + 1;
    for (int t = 0; t < ntiles; ++t) {
        const int t0 = t * KBT;
        __syncthreads();
        for (int slot = tid; slot < KBT * 16; slot += 256) {
            const int r = slot >> 4, seg = slot & 15;
            uint4 v1 = *(const uint4*)(kw + (rowbase + t0 + r) * DMODEL + coff + seg * 8);
            float4 a, c; cvt8(v1, a, c);
            *(float4*)&Ks[r][seg * 8] = a;
            *(float4*)&Ks[r][seg * 8 + 4] = c;
            uint4 v2 = *(const uint4*)(vw + (rowbase + t0 + r) * DMODEL + coff + seg * 8);
            cvt8(v2, a, c);
            *(float4*)&Vs[r][seg * 8] = a;
            *(float4*)&Vs[r][seg * 8 + 4] = c;
        }
        __syncthreads();
#pragma unroll
        for (int r8 = 0; r8 < 8; ++r8) {
            const int rl = wave * 8 + r8;
            const int rpos = q0 + rl;
            if (rpos < t0) continue;    // wave-uniform: tile fully masked for this row
            // score: one dot per lane (its half, its key)
            float s = 0.f;
#pragma unroll
            for (int i4 = 0; i4 < 16; ++i4) {
                const float4 kk = *(const float4*)&Ks[j][which * 64 + i4 * 4];
                const float4 qq = *(const float4*)&Qs[rl][which * 64 + i4 * 4];
                s += qq.x * kk.x + qq.y * kk.y + qq.z * kk.z + qq.w * kk.w;
            }
            s *= 0.125f;   // hd^-0.5
            const bool valid = (t0 + j) <= rpos;
            s = valid ? s : -1e30f;
            float mt = s;
#pragma unroll
            for (int off = 16; off; off >>= 1) mt = fmaxf(mt, __shfl_xor(mt, off));
            const float mn = fmaxf(m_[r8], mt);
            const float p = valid ? __expf(s - mn) : 0.f;
            const float alpha = __expf(m_[r8] - mn);
            m_[r8] = mn;
            float sp = p;
#pragma unroll
            for (int off = 16; off; off >>= 1) sp += __shfl_xor(sp, off);
            l_[r8] = l_[r8] * alpha + sp;
            Ps[wave][which][j] = p;
            const float a1 = __shfl(alpha, 0);
            const float a2 = __shfl(alpha, 32);
            o00[r8] *= a1; o01[r8] *= a1; o10[r8] *= a2; o11[r8] *= a2;
            float c00 = 0.f, c01 = 0.f, c10 = 0.f, c11 = 0.f;
#pragma unroll 8
            for (int jj = 0; jj < KBT; ++jj) {
                const float p1 = Ps[wave][0][jj];
                const float p2 = Ps[wave][1][jj];
                const float2 vv = *(const float2*)&Vs[jj][lane * 2];
                c00 += p1 * vv.x; c01 += p1 * vv.y;
                c10 += p2 * vv.x; c11 += p2 * vv.y;
            }
            o00[r8] += c00; o01[r8] += c01; o10[r8] += c10; o11[r8] += c11;
        }
    }
#pragma unroll
    for (int r8 = 0; r8 < 8; ++r8) {
        const int rpos = q0 + wave * 8 + r8;
        const float l1 = __shfl(l_[r8], 0);
        const float l2 = __shfl(l_[r8], 32);
        const size_t idx = (rowbase + rpos) * DMODEL + coff + lane * 2;
        float2 w1; w1.x = o00[r8] / l1; w1.y = o01[r8] / l1;
        float2 w2; w2.x = o10[r8] / l2; w2.y = o11[r8] / l2;
        *(float2*)&attn1[idx] = w1;
        *(float2*)&attn2[idx] = w2;
    }
}

// ---------- combine: y = rmsnorm(attn1 - lam*attn2)*w + b, scaled, -> bf16 ----------
__global__ __launch_bounds__(256) void combine_kernel(const float* __restrict__ a1,
                                                      const float* __restrict__ a2,
                                                      const float* __restrict__ lamp,
                                                      const float* __restrict__ lnw,
                                                      const float* __restrict__ lnb,
                                                      u16* __restrict__ yb) {
    const int row = blockIdx.x;
    const int tid = threadIdx.x;
    const int h = tid >> 4, sub = tid & 15;
    const float lam = lamp[0];
    const size_t base = (size_t)row * DMODEL + h * 128 + sub * 8;
    const float4 p = *(const float4*)(a1 + base);
    const float4 q = *(const float4*)(a1 + base + 4);
    const float4 r = *(const float4*)(a2 + base);
    const float4 s = *(const float4*)(a2 + base + 4);
    float v[8];
    v[0] = p.x - lam * r.x; v[1] = p.y - lam * r.y; v[2] = p.z - lam * r.z; v[3] = p.w - lam * r.w;
    v[4] = q.x - lam * s.x; v[5] = q.y - lam * s.y; v[6] = q.z - lam * s.z; v[7] = q.w - lam * s.w;
    float ss = 0.f;
#pragma unroll
    for (int i = 0; i < 8; ++i) ss += v[i] * v[i];
#pragma unroll
    for (int off = 1; off < 16; off <<= 1) ss += __shfl_xor(ss, off);
    const float inv = rsqrtf(ss * (1.f / 128.f) + 1e-8f) * OUT_SCALE;
    const int d = sub * 8;
    uint4 o;
    u16 e[8];
#pragma unroll
    for (int i = 0; i < 8; ++i) e[i] = f2bf(v[i] * inv * lnw[d + i] + lnb[d + i] * OUT_SCALE);
    o.x = (u32)e[0] | ((u32)e[1] << 16);
    o.y = (u32)e[2] | ((u32)e[3] << 16);
    o.z = (u32)e[4] | ((u32)e[5] << 16);
    o.w = (u32)e[6] | ((u32)e[7] << 16);
    *(uint4*)(yb + base) = o;
}

// ---------- workspace layout (bytes) ----------
#define WT_OFF   0ull                 // 4 x 2048x2048 bf16 = 33554432
#define XB_OFF   33554432ull          // 4096x2048 bf16 (reused as yb)
#define Q_OFF    50331648ull          // 4096x2048 bf16
#define K_OFF    67108864ull
#define V_OFF    83886080ull
#define A1_OFF   100663296ull         // 4096x2048 f32
#define A2_OFF   134217728ull
#define LAM_OFF  167772160ull
#define WS_NEED  167772416ull

extern "C" void kernel_launch(void* const* d_in, const int* in_sizes, int n_in,
                              void* d_out, int out_size, void* d_ws, size_t ws_size,
                              hipStream_t stream) {
    if (ws_size < WS_NEED) return;  // cannot run without scratch
    const float* x   = (const float*)d_in[0];
    const float* Wq  = (const float*)d_in[1];
    const float* Wk  = (const float*)d_in[2];
    const float* Wv  = (const float*)d_in[3];
    const float* Wo  = (const float*)d_in[4];
    const float* lq1 = (const float*)d_in[5];
    const float* lk1 = (const float*)d_in[6];
    const float* lq2 = (const float*)d_in[7];
    const float* lk2 = (const float*)d_in[8];
    const float* lnw = (const float*)d_in[9];
    const float* lnb = (const float*)d_in[10];

    char* ws = (char*)d_ws;
    u16* wt  = (u16*)(ws + WT_OFF);
    u16* xb  = (u16*)(ws + XB_OFF);   // also yb after combine
    u16* qb  = (u16*)(ws + Q_OFF);
    u16* kb  = (u16*)(ws + K_OFF);
    u16* vb  = (u16*)(ws + V_OFF);
    float* a1  = (float*)(ws + A1_OFF);
    float* a2  = (float*)(ws + A2_OFF);
    float* lam = (float*)(ws + LAM_OFF);
    float* out = (float*)d_out;

    // 1. transpose + convert the 4 weight matrices
    transpose_w<<<dim3(64, 64, 4), dim3(32, 8, 1), 0, stream>>>(Wq, Wk, Wv, Wo, wt);
    // 2. x -> bf16
    cvt_x<<<dim3(4096), dim3(256), 0, stream>>>(x, xb);
    // 3. q,k,v = x @ {Wq,Wk,Wv}   (bf16 out)
    gemm_bt<true><<<dim3(16, 32, 3), dim3(256), 0, stream>>>(xb, wt, qb);
    // 4. RoPE in place on q and k
    rope_kernel<<<dim3(4096, 2), dim3(256), 0, stream>>>(qb, kb);
    // 5. lambda
    lam_kernel<<<dim3(1), dim3(64), 0, stream>>>(lq1, lk1, lq2, lk2, lam);
    // 6. dual causal attention
    attn_kernel<<<dim3(SQ / QB, 32), dim3(256), 0, stream>>>(qb, kb, vb, a1, a2);
    // 7. combine + rmsnorm -> yb (reuses xb buffer)
    combine_kernel<<<dim3(4096), dim3(256), 0, stream>>>(a1, a2, lam, lnw, lnb, xb);
    // 8. out = y @ Wo  (f32 out)
    gemm_bt<false><<<dim3(16, 32, 1), dim3(256), 0, stream>>>(xb, wt + 3ull * DMODEL * DMODEL, out);
}

// Round 2
// 827.321 us; speedup vs baseline: 3.5845x; 3.5845x over previous
//
#include <hip/hip_runtime.h>

typedef unsigned short u16;
typedef unsigned int   u32;
typedef short bf16x8 __attribute__((ext_vector_type(8)));
typedef float f32x4  __attribute__((ext_vector_type(4)));

#define SQ 2048            // sequence length
#define DMODEL 2048        // embed dim
#define NROWS 4096         // b*s
#define LAMBDA_INIT 0.7836057665316245f
#define OUT_SCALE   0.21639423346837552f   // 1 - LAMBDA_INIT

// ---------- helpers ----------
__device__ __forceinline__ float bf2f(u16 u) {
    union { u32 u; float f; } x; x.u = ((u32)u) << 16; return x.f;
}
__device__ __forceinline__ u16 f2bf(float f) {
    union { float f; u32 u; } x; x.f = f;
    u32 r = x.u + 0x7fffu + ((x.u >> 16) & 1u);   // RNE
    return (u16)(r >> 16);
}

// ---------- W transpose + bf16 convert: Wt[n][k] = bf16(W[k][n]) ----------
__global__ __launch_bounds__(256) void transpose_w(const float* __restrict__ W0,
                                                   const float* __restrict__ W1,
                                                   const float* __restrict__ W2,
                                                   const float* __restrict__ W3,
                                                   u16* __restrict__ out) {
    __shared__ float tile[32][33];
    const int z = blockIdx.z;
    const float* W = (z == 0) ? W0 : (z == 1) ? W1 : (z == 2) ? W2 : W3;
    u16* O = out + (size_t)z * DMODEL * DMODEL;
    const int tx = threadIdx.x, ty = threadIdx.y;
    const int bx = blockIdx.x, by = blockIdx.y;
#pragma unroll
    for (int j = 0; j < 4; ++j)
        tile[ty + j * 8][tx] = W[(size_t)(by * 32 + ty + j * 8) * DMODEL + bx * 32 + tx];
    __syncthreads();
#pragma unroll
    for (int j = 0; j < 4; ++j)
        O[(size_t)(bx * 32 + ty + j * 8) * DMODEL + by * 32 + tx] = f2bf(tile[tx][ty + j * 8]);
}

// ---------- x -> bf16 ----------
__global__ __launch_bounds__(256) void cvt_x(const float* __restrict__ x, u16* __restrict__ xb) {
    const size_t i = ((size_t)blockIdx.x * 256 + threadIdx.x) * 8;
    float4 a = *(const float4*)(x + i);
    float4 b = *(const float4*)(x + i + 4);
    uint4 o;
    o.x = (u32)f2bf(a.x) | ((u32)f2bf(a.y) << 16);
    o.y = (u32)f2bf(a.z) | ((u32)f2bf(a.w) << 16);
    o.z = (u32)f2bf(b.x) | ((u32)f2bf(b.y) << 16);
    o.w = (u32)f2bf(b.z) | ((u32)f2bf(b.w) << 16);
    *(uint4*)(xb + i) = o;
}

// ---------- MFMA GEMM: C = A(MxK) x Bt(NxK)^T ; M=4096,N=2048,K=2048 ----------
template <bool OUT_BF16>
__global__ __launch_bounds__(256) void gemm_bt(const u16* __restrict__ A,
                                               const u16* __restrict__ Bt0,
                                               void* __restrict__ C0) {
    __shared__ u16 As[128 * 40];
    __shared__ u16 Bs[128 * 40];
    const int tid  = threadIdx.x;
    const int lane = tid & 63, wave = tid >> 6;
    const int wm = wave & 1, wn = wave >> 1;
    const int l15 = lane & 15, quad = lane >> 4;
    const int tm = blockIdx.y * 128, tn = blockIdx.x * 128;
    const u16* Bt = Bt0 + (size_t)blockIdx.z * DMODEL * DMODEL;

    f32x4 acc[4][4] = {};

    for (int k0 = 0; k0 < DMODEL; k0 += 32) {
#pragma unroll
        for (int p = 0; p < 2; ++p) {
            const int slot = p * 256 + tid;
            const int r = slot >> 2, cg = slot & 3;
            const uint4 va = *(const uint4*)(A  + (size_t)(tm + r) * DMODEL + k0 + cg * 8);
            *(uint4*)(As + r * 40 + cg * 8) = va;
            const uint4 vb = *(const uint4*)(Bt + (size_t)(tn + r) * DMODEL + k0 + cg * 8);
            *(uint4*)(Bs + r * 40 + cg * 8) = vb;
        }
        __syncthreads();
        bf16x8 af[4], bfr[4];
#pragma unroll
        for (int mb = 0; mb < 4; ++mb)
            af[mb] = *(const bf16x8*)(As + (wm * 64 + mb * 16 + l15) * 40 + quad * 8);
#pragma unroll
        for (int nb = 0; nb < 4; ++nb)
            bfr[nb] = *(const bf16x8*)(Bs + (wn * 64 + nb * 16 + l15) * 40 + quad * 8);
#pragma unroll
        for (int mb = 0; mb < 4; ++mb)
#pragma unroll
            for (int nb = 0; nb < 4; ++nb)
                acc[mb][nb] = __builtin_amdgcn_mfma_f32_16x16x32_bf16(af[mb], bfr[nb], acc[mb][nb], 0, 0, 0);
        __syncthreads();
    }
#pragma unroll
    for (int mb = 0; mb < 4; ++mb)
#pragma unroll
        for (int nb = 0; nb < 4; ++nb)
#pragma unroll
            for (int r = 0; r < 4; ++r) {
                const int row = tm + wm * 64 + mb * 16 + quad * 4 + r;
                const int col = tn + wn * 64 + nb * 16 + l15;
                const float v = acc[mb][nb][r];
                if (OUT_BF16) {
                    u16* C = (u16*)C0 + (size_t)blockIdx.z * NROWS * DMODEL;
                    C[(size_t)row * DMODEL + col] = f2bf(v);
                } else {
                    float* C = (float*)C0;
                    C[(size_t)row * DMODEL + col] = v;
                }
            }
}

// ---------- RoPE in place on bf16 q or k ----------
__global__ __launch_bounds__(256) void rope_kernel(u16* __restrict__ qw, u16* __restrict__ kw) {
    const int row = blockIdx.x;
    const int spos = row & (SQ - 1);
    u16* buf = blockIdx.y ? kw : qw;
    for (int idx = threadIdx.x; idx < 1024; idx += 256) {
        const int h2 = idx >> 5, i = idx & 31;
        const size_t base = (size_t)row * DMODEL + h2 * 64 + 2 * i;
        const float x1 = bf2f(buf[base]), x2 = bf2f(buf[base + 1]);
        const float f = (float)spos * exp2f(-0.41524101186092034f * (float)i);
        const float c = cosf(f), sn = sinf(f);
        buf[base]     = f2bf(x1 * c - x2 * sn);
        buf[base + 1] = f2bf(x2 * c + x1 * sn);
    }
}

// ---------- lambda scalar ----------
__global__ void lam_kernel(const float* __restrict__ lq1, const float* __restrict__ lk1,
                           const float* __restrict__ lq2, const float* __restrict__ lk2,
                           float* __restrict__ out) {
    const int l = threadIdx.x;  // 64
    float v1 = lq1[l] * lk1[l];
    float v2 = lq2[l] * lk2[l];
#pragma unroll
    for (int off = 32; off; off >>= 1) {
        v1 += __shfl_xor(v1, off);
        v2 += __shfl_xor(v2, off);
    }
    if (l == 0) out[0] = __expf(v1) - __expf(v2) + LAMBDA_INIT;
}

// ---------- V transpose: vtg[bh][128 dims][2048 keys] ----------
__global__ __launch_bounds__(256) void vtrans(const u16* __restrict__ vb, u16* __restrict__ vtg) {
    __shared__ u16 tile[64][72];
    const int bh = blockIdx.z;
    const int b = bh >> 4, h = bh & 15;
    const int s0 = blockIdx.x * 64, d0 = blockIdx.y * 64;
    const size_t rowbase = (size_t)b * SQ;
    const int tid = threadIdx.x;
#pragma unroll
    for (int it = 0; it < 2; ++it) {
        const int slot = it * 256 + tid;
        const int key = slot >> 3, dg = slot & 7;
        *(uint4*)&tile[key][dg * 8] =
            *(const uint4*)(vb + (rowbase + s0 + key) * DMODEL + h * 128 + d0 + dg * 8);
    }
    __syncthreads();
#pragma unroll
    for (int it = 0; it < 2; ++it) {
        const int slot = it * 256 + tid;
        const int d = slot >> 3, kg = slot & 7;
        u16 e[8];
#pragma unroll
        for (int j = 0; j < 8; ++j) e[j] = tile[kg * 8 + j][d];
        uint4 o;
        o.x = (u32)e[0] | ((u32)e[1] << 16);
        o.y = (u32)e[2] | ((u32)e[3] << 16);
        o.z = (u32)e[4] | ((u32)e[5] << 16);
        o.w = (u32)e[6] | ((u32)e[7] << 16);
        *(uint4*)(vtg + ((size_t)bh * 128 + d0 + d) * SQ + s0 + kg * 8) = o;
    }
}

// ---------- MFMA flash attention (dual softmax) + fused combine/RMSNorm ----------
// grid (32, 32): block = (b,h) x 64 q rows; wave w owns q rows [q0+w*16, q0+w*16+16).
// MFMA layouts (HW-verified): A: m=lane&15, k=quad*8+j ; C/D: col=lane&15, row=quad*4+r.
__global__ __launch_bounds__(256) void attn_kernel(const u16* __restrict__ qw,
                                                   const u16* __restrict__ kw,
                                                   const u16* __restrict__ vtg,
                                                   const float* __restrict__ lamp,
                                                   const float* __restrict__ lnw,
                                                   const float* __restrict__ lnb,
                                                   u16* __restrict__ yb) {
    __shared__ u16 Ks[64 * 136];     // [key][128 dims + 8 pad]
    __shared__ u16 Vts[128 * 72];    // [dim][64 keys + 8 pad]
    __shared__ u16 Pls[4][16 * 72];  // per-wave [q16][64 keys + 8 pad]

    const int tid = threadIdx.x, lane = tid & 63, wave = tid >> 6;
    const int l15 = lane & 15, quad = lane >> 4;
    const int q0 = (31 - blockIdx.x) * 64;   // heavy blocks first
    const int bh = blockIdx.y, b = bh >> 4, h = bh & 15;
    const size_t rowbase = (size_t)b * SQ;
    const int coff = h * 128;

    // Q fragments (A layout), persistent: [half][kstep]
    bf16x8 qf[2][2];
    {
        const size_t qbase = (rowbase + q0 + wave * 16 + l15) * DMODEL + coff + quad * 8;
#pragma unroll
        for (int hf = 0; hf < 2; ++hf)
#pragma unroll
            for (int ks = 0; ks < 2; ++ks)
                qf[hf][ks] = *(const bf16x8*)(qw + qbase + hf * 64 + ks * 32);
    }

    f32x4 O[2][8] = {};
    float mm[2][4], ll[2][4];
#pragma unroll
    for (int hf = 0; hf < 2; ++hf)
#pragma unroll
        for (int r = 0; r < 4; ++r) { mm[hf][r] = -1e30f; ll[hf][r] = 0.f; }

    const int nt = q0 / 64 + 1;
    for (int t = 0; t < nt; ++t) {
        const int t0 = t * 64;
        __syncthreads();
        // stage K (both halves) and V^T tiles
#pragma unroll
        for (int it = 0; it < 4; ++it) {
            const int slot = it * 256 + tid;
            {
                const int key = slot >> 4, cg = slot & 15;
                *(uint4*)&Ks[key * 136 + cg * 8] =
                    *(const uint4*)(kw + (rowbase + t0 + key) * DMODEL + coff + cg * 8);
            }
            {
                const int d = slot >> 3, kg = slot & 7;
                *(uint4*)&Vts[d * 72 + kg * 8] =
                    *(const uint4*)(vtg + ((size_t)bh * 128 + d) * SQ + t0 + kg * 8);
            }
        }
        __syncthreads();
        const bool maskt = (t == nt - 1);   // only diagonal tile needs masking

#pragma unroll
        for (int hf = 0; hf < 2; ++hf) {
            // ---- S = Q_hf K_hf^T (16 q x 64 keys per wave) ----
            f32x4 S[4] = {};
#pragma unroll
            for (int nb = 0; nb < 4; ++nb)
#pragma unroll
                for (int ks = 0; ks < 2; ++ks) {
                    bf16x8 kf = *(const bf16x8*)&Ks[(nb * 16 + l15) * 136 + hf * 64 + ks * 32 + quad * 8];
                    S[nb] = __builtin_amdgcn_mfma_f32_16x16x32_bf16(qf[hf][ks], kf, S[nb], 0, 0, 0);
                }
            // ---- scale + causal mask + row max ----
            float mt[4];
#pragma unroll
            for (int r = 0; r < 4; ++r) mt[r] = -1e30f;
#pragma unroll
            for (int nb = 0; nb < 4; ++nb)
#pragma unroll
                for (int r = 0; r < 4; ++r) {
                    float s = S[nb][r] * 0.125f;
                    if (maskt && (nb * 16 + l15 > wave * 16 + quad * 4 + r)) s = -1e30f;
                    S[nb][r] = s;
                    mt[r] = fmaxf(mt[r], s);
                }
#pragma unroll
            for (int r = 0; r < 4; ++r)
#pragma unroll
                for (int off = 1; off < 16; off <<= 1)
                    mt[r] = fmaxf(mt[r], __shfl_xor(mt[r], off));
            // ---- online softmax update ----
            float alpha[4], ps[4];
#pragma unroll
            for (int r = 0; r < 4; ++r) {
                const float mn = fmaxf(mm[hf][r], mt[r]);
                alpha[r] = __expf(mm[hf][r] - mn);
                mm[hf][r] = mn;
                ps[r] = 0.f;
            }
#pragma unroll
            for (int nb = 0; nb < 4; ++nb)
#pragma unroll
                for (int r = 0; r < 4; ++r) {
                    const float p = __expf(S[nb][r] - mm[hf][r]);
                    const u16 pq = f2bf(p);
                    ps[r] += bf2f(pq);    // sum the quantized p for consistent normalization
                    Pls[wave][(quad * 4 + r) * 72 + nb * 16 + l15] = pq;
                }
#pragma unroll
            for (int r = 0; r < 4; ++r) {
#pragma unroll
                for (int off = 1; off < 16; off <<= 1) ps[r] += __shfl_xor(ps[r], off);
                ll[hf][r] = ll[hf][r] * alpha[r] + ps[r];
            }
            // ---- rescale O, then O += P V ----
#pragma unroll
            for (int nb = 0; nb < 8; ++nb)
#pragma unroll
                for (int r = 0; r < 4; ++r) O[hf][nb][r] *= alpha[r];
            bf16x8 pf[2];
#pragma unroll
            for (int ks = 0; ks < 2; ++ks)
                pf[ks] = *(const bf16x8*)&Pls[wave][l15 * 72 + ks * 32 + quad * 8];
#pragma unroll
            for (int nb = 0; nb < 8; ++nb)
#pragma unroll
                for (int ks = 0; ks < 2; ++ks) {
                    bf16x8 vf = *(const bf16x8*)&Vts[(nb * 16 + l15) * 72 + ks * 32 + quad * 8];
                    O[hf][nb] = __builtin_amdgcn_mfma_f32_16x16x32_bf16(pf[ks], vf, O[hf][nb], 0, 0, 0);
                }
        }
    }

    // ---- epilogue: y = rmsnorm(O1/l1 - lam*O2/l2) * w + b, * OUT_SCALE, bf16 ----
    const float lam = lamp[0];
    float inl1[4], inl2[4];
#pragma unroll
    for (int r = 0; r < 4; ++r) { inl1[r] = 1.f / ll[0][r]; inl2[r] = 1.f / ll[1][r]; }
    float vv[8][4], ss[4] = {0.f, 0.f, 0.f, 0.f};
#pragma unroll
    for (int nb = 0; nb < 8; ++nb)
#pragma unroll
        for (int r = 0; r < 4; ++r) {
            const float v = O[0][nb][r] * inl1[r] - lam * O[1][nb][r] * inl2[r];
            vv[nb][r] = v;
            ss[r] += v * v;
        }
#pragma unroll
    for (int r = 0; r < 4; ++r) {
#pragma unroll
        for (int off = 1; off < 16; off <<= 1) ss[r] += __shfl_xor(ss[r], off);
        ss[r] = rsqrtf(ss[r] * (1.f / 128.f) + 1e-8f) * OUT_SCALE;
    }
#pragma unroll
    for (int nb = 0; nb < 8; ++nb) {
        const int d = nb * 16 + l15;
        const float w = lnw[d], bb = lnb[d] * OUT_SCALE;
#pragma unroll
        for (int r = 0; r < 4; ++r) {
            const size_t row = rowbase + q0 + wave * 16 + quad * 4 + r;
            yb[row * DMODEL + coff + d] = f2bf(vv[nb][r] * ss[r] * w + bb);
        }
    }
}

// ---------- workspace layout (bytes) ----------
#define WT_OFF   0ull                 // 4 x 2048x2048 bf16 = 32 MB
#define XB_OFF   33554432ull          // 4096x2048 bf16 (xb, reused as yb)
#define Q_OFF    50331648ull          // 4096x2048 bf16
#define K_OFF    67108864ull
#define V_OFF    83886080ull
#define VT_OFF   100663296ull         // 32 bh x 128 x 2048 bf16 = 16 MB
#define LAM_OFF  117440512ull
#define WS_NEED  117440768ull

extern "C" void kernel_launch(void* const* d_in, const int* in_sizes, int n_in,
                              void* d_out, int out_size, void* d_ws, size_t ws_size,
                              hipStream_t stream) {
    if (ws_size < WS_NEED) return;
    const float* x   = (const float*)d_in[0];
    const float* Wq  = (const float*)d_in[1];
    const float* Wk  = (const float*)d_in[2];
    const float* Wv  = (const float*)d_in[3];
    const float* Wo  = (const float*)d_in[4];
    const float* lq1 = (const float*)d_in[5];
    const float* lk1 = (const float*)d_in[6];
    const float* lq2 = (const float*)d_in[7];
    const float* lk2 = (const float*)d_in[8];
    const float* lnw = (const float*)d_in[9];
    const float* lnb = (const float*)d_in[10];

    char* ws = (char*)d_ws;
    u16* wt  = (u16*)(ws + WT_OFF);
    u16* xb  = (u16*)(ws + XB_OFF);   // also yb after attention
    u16* qb  = (u16*)(ws + Q_OFF);
    u16* kb  = (u16*)(ws + K_OFF);
    u16* vb  = (u16*)(ws + V_OFF);
    u16* vtg = (u16*)(ws + VT_OFF);
    float* lam = (float*)(ws + LAM_OFF);
    float* out = (float*)d_out;

    // 1. transpose + convert weights
    transpose_w<<<dim3(64, 64, 4), dim3(32, 8, 1), 0, stream>>>(Wq, Wk, Wv, Wo, wt);
    // 2. x -> bf16
    cvt_x<<<dim3(4096), dim3(256), 0, stream>>>(x, xb);
    // 3. q,k,v GEMMs (bf16 out)
    gemm_bt<true><<<dim3(16, 32, 3), dim3(256), 0, stream>>>(xb, wt, qb);
    // 4. RoPE in place on q and k
    rope_kernel<<<dim3(4096, 2), dim3(256), 0, stream>>>(qb, kb);
    // 5. lambda
    lam_kernel<<<dim3(1), dim3(64), 0, stream>>>(lq1, lk1, lq2, lk2, lam);
    // 6. V transpose for PV MFMA B-operand
    vtrans<<<dim3(32, 2, 32), dim3(256), 0, stream>>>(vb, vtg);
    // 7. MFMA flash attention + fused combine/RMSNorm -> yb (bf16, reuses xb)
    attn_kernel<<<dim3(32, 32), dim3(256), 0, stream>>>(qb, kb, vtg, lam, lnw, lnb, xb);
    // 8. out = y @ Wo  (f32 out)
    gemm_bt<false><<<dim3(16, 32, 1), dim3(256), 0, stream>>>(xb, wt + 3ull * DMODEL * DMODEL, out);
}

// Round 3
// 545.664 us; speedup vs baseline: 5.4348x; 1.5162x over previous
//
#include <hip/hip_runtime.h>

typedef unsigned short u16;
typedef unsigned int   u32;
typedef short bf16x8 __attribute__((ext_vector_type(8)));
typedef float f32x4  __attribute__((ext_vector_type(4)));

#define SQ 2048            // sequence length
#define DMODEL 2048        // embed dim
#define NROWS 4096         // b*s
#define LAMBDA_INIT 0.7836057665316245f
#define OUT_SCALE   0.21639423346837552f   // 1 - LAMBDA_INIT

// ---------- helpers ----------
__device__ __forceinline__ float bf2f(u16 u) {
    union { u32 u; float f; } x; x.u = ((u32)u) << 16; return x.f;
}
__device__ __forceinline__ u16 f2bf(float f) {
    union { float f; u32 u; } x; x.f = f;
    u32 r = x.u + 0x7fffu + ((x.u >> 16) & 1u);   // RNE
    return (u16)(r >> 16);
}

// async global->LDS, 16B per lane. lds base must be wave-uniform; HW scatters
// lane i -> base + 16*i.  [m03/m97-verified path]
__device__ __forceinline__ void gload_lds16(const void* g, void* l) {
    __builtin_amdgcn_global_load_lds((const __attribute__((address_space(1))) void*)g,
                                     (__attribute__((address_space(3))) void*)l,
                                     16, 0, 0);
}

// ---------- W transpose + bf16 convert: Wt[n][k] = bf16(W[k][n]) ----------
__global__ __launch_bounds__(256) void transpose_w(const float* __restrict__ W0,
                                                   const float* __restrict__ W1,
                                                   const float* __restrict__ W2,
                                                   const float* __restrict__ W3,
                                                   u16* __restrict__ out) {
    __shared__ float tile[32][33];
    const int z = blockIdx.z;
    const float* W = (z == 0) ? W0 : (z == 1) ? W1 : (z == 2) ? W2 : W3;
    u16* O = out + (size_t)z * DMODEL * DMODEL;
    const int tx = threadIdx.x, ty = threadIdx.y;
    const int bx = blockIdx.x, by = blockIdx.y;
#pragma unroll
    for (int j = 0; j < 4; ++j)
        tile[ty + j * 8][tx] = W[(size_t)(by * 32 + ty + j * 8) * DMODEL + bx * 32 + tx];
    __syncthreads();
#pragma unroll
    for (int j = 0; j < 4; ++j)
        O[(size_t)(bx * 32 + ty + j * 8) * DMODEL + by * 32 + tx] = f2bf(tile[tx][ty + j * 8]);
}

// ---------- x -> bf16 ----------
__global__ __launch_bounds__(256) void cvt_x(const float* __restrict__ x, u16* __restrict__ xb) {
    const size_t i = ((size_t)blockIdx.x * 256 + threadIdx.x) * 8;
    float4 a = *(const float4*)(x + i);
    float4 b = *(const float4*)(x + i + 4);
    uint4 o;
    o.x = (u32)f2bf(a.x) | ((u32)f2bf(a.y) << 16);
    o.y = (u32)f2bf(a.z) | ((u32)f2bf(a.w) << 16);
    o.z = (u32)f2bf(b.x) | ((u32)f2bf(b.y) << 16);
    o.w = (u32)f2bf(b.z) | ((u32)f2bf(b.w) << 16);
    *(uint4*)(xb + i) = o;
}

// ---------- MFMA GEMM (m97 pattern): C = A(MxK) x Bt(NxK)^T ----------
// 128x128 tile, BK=32, global_load_lds width=16 staging, unpadded LDS.
template <bool OUT_BF16>
__global__ __launch_bounds__(256) void gemm_bt(const u16* __restrict__ A,
                                               const u16* __restrict__ Bt0,
                                               void* __restrict__ C0) {
    __shared__ u16 As[128 * 32];   // 8 KB, NO padding (lds-scatter is lane-contiguous)
    __shared__ u16 Bs[128 * 32];
    const int tid  = threadIdx.x;
    const int lane = tid & 63, wave = tid >> 6;
    const int wm = wave & 1, wn = wave >> 1;
    const int l15 = lane & 15, quad = lane >> 4;
    const int tm = blockIdx.y * 128, tn = blockIdx.x * 128;
    const u16* Bt = Bt0 + (size_t)blockIdx.z * DMODEL * DMODEL;

    // staging geometry: chunk = 16 rows x 32 cols = 1 KB = one wave-issue.
    const int r_l = lane >> 2, c_l = lane & 3;   // row-in-chunk, col-group

    f32x4 acc[4][4] = {};

    for (int k0 = 0; k0 < DMODEL; k0 += 32) {
#pragma unroll
        for (int c = 0; c < 2; ++c) {
            const int chunk = wave * 2 + c;
            const int row = chunk * 16 + r_l;
            gload_lds16(A  + (size_t)(tm + row) * DMODEL + k0 + c_l * 8, &As[chunk * 512]);
            gload_lds16(Bt + (size_t)(tn + row) * DMODEL + k0 + c_l * 8, &Bs[chunk * 512]);
        }
        __syncthreads();
        bf16x8 af[4], bfr[4];
#pragma unroll
        for (int mb = 0; mb < 4; ++mb)
            af[mb] = *(const bf16x8*)(As + (wm * 64 + mb * 16 + l15) * 32 + quad * 8);
#pragma unroll
        for (int nb = 0; nb < 4; ++nb)
            bfr[nb] = *(const bf16x8*)(Bs + (wn * 64 + nb * 16 + l15) * 32 + quad * 8);
#pragma unroll
        for (int mb = 0; mb < 4; ++mb)
#pragma unroll
            for (int nb = 0; nb < 4; ++nb)
                acc[mb][nb] = __builtin_amdgcn_mfma_f32_16x16x32_bf16(af[mb], bfr[nb], acc[mb][nb], 0, 0, 0);
        __syncthreads();
    }
#pragma unroll
    for (int mb = 0; mb < 4; ++mb)
#pragma unroll
        for (int nb = 0; nb < 4; ++nb)
#pragma unroll
            for (int r = 0; r < 4; ++r) {
                const int row = tm + wm * 64 + mb * 16 + quad * 4 + r;
                const int col = tn + wn * 64 + nb * 16 + l15;
                const float v = acc[mb][nb][r];
                if (OUT_BF16) {
                    u16* C = (u16*)C0 + (size_t)blockIdx.z * NROWS * DMODEL;
                    C[(size_t)row * DMODEL + col] = f2bf(v);
                } else {
                    float* C = (float*)C0;
                    C[(size_t)row * DMODEL + col] = v;
                }
            }
}

// ---------- RoPE in place on bf16 q or k ----------
__global__ __launch_bounds__(256) void rope_kernel(u16* __restrict__ qw, u16* __restrict__ kw) {
    const int row = blockIdx.x;
    const int spos = row & (SQ - 1);
    u16* buf = blockIdx.y ? kw : qw;
    for (int idx = threadIdx.x; idx < 1024; idx += 256) {
        const int h2 = idx >> 5, i = idx & 31;
        const size_t base = (size_t)row * DMODEL + h2 * 64 + 2 * i;
        const float x1 = bf2f(buf[base]), x2 = bf2f(buf[base + 1]);
        const float f = (float)spos * exp2f(-0.41524101186092034f * (float)i);
        const float c = cosf(f), sn = sinf(f);
        buf[base]     = f2bf(x1 * c - x2 * sn);
        buf[base + 1] = f2bf(x2 * c + x1 * sn);
    }
}

// ---------- lambda scalar ----------
__global__ void lam_kernel(const float* __restrict__ lq1, const float* __restrict__ lk1,
                           const float* __restrict__ lq2, const float* __restrict__ lk2,
                           float* __restrict__ out) {
    const int l = threadIdx.x;  // 64
    float v1 = lq1[l] * lk1[l];
    float v2 = lq2[l] * lk2[l];
#pragma unroll
    for (int off = 32; off; off >>= 1) {
        v1 += __shfl_xor(v1, off);
        v2 += __shfl_xor(v2, off);
    }
    if (l == 0) out[0] = __expf(v1) - __expf(v2) + LAMBDA_INIT;
}

// ---------- V transpose: vtg[bh][128 dims][2048 keys] ----------
__global__ __launch_bounds__(256) void vtrans(const u16* __restrict__ vb, u16* __restrict__ vtg) {
    __shared__ u16 tile[64][72];
    const int bh = blockIdx.z;
    const int b = bh >> 4, h = bh & 15;
    const int s0 = blockIdx.x * 64, d0 = blockIdx.y * 64;
    const size_t rowbase = (size_t)b * SQ;
    const int tid = threadIdx.x;
#pragma unroll
    for (int it = 0; it < 2; ++it) {
        const int slot = it * 256 + tid;
        const int key = slot >> 3, dg = slot & 7;
        *(uint4*)&tile[key][dg * 8] =
            *(const uint4*)(vb + (rowbase + s0 + key) * DMODEL + h * 128 + d0 + dg * 8);
    }
    __syncthreads();
#pragma unroll
    for (int it = 0; it < 2; ++it) {
        const int slot = it * 256 + tid;
        const int d = slot >> 3, kg = slot & 7;
        u16 e[8];
#pragma unroll
        for (int j = 0; j < 8; ++j) e[j] = tile[kg * 8 + j][d];
        uint4 o;
        o.x = (u32)e[0] | ((u32)e[1] << 16);
        o.y = (u32)e[2] | ((u32)e[3] << 16);
        o.z = (u32)e[4] | ((u32)e[5] << 16);
        o.w = (u32)e[6] | ((u32)e[7] << 16);
        *(uint4*)(vtg + ((size_t)bh * 128 + d0 + d) * SQ + s0 + kg * 8) = o;
    }
}

// ---------- MFMA flash attention (dual softmax) + fused combine/RMSNorm ----------
// Balanced causal pairing: block bx in [0,16) does q-strips bx and 31-bx
// sequentially -> every block = 33 K-tiles. grid (16, 32).
// LDS xor-swizzle: logical col-group cg stored at cg ^ (row & 7)  -> <=2-way banks.
__global__ __launch_bounds__(256) void attn_kernel(const u16* __restrict__ qw,
                                                   const u16* __restrict__ kw,
                                                   const u16* __restrict__ vtg,
                                                   const float* __restrict__ lamp,
                                                   const float* __restrict__ lnw,
                                                   const float* __restrict__ lnb,
                                                   u16* __restrict__ yb) {
    __shared__ u16 Ks[64 * 128];     // [key][16 swizzled col-groups of 8]
    __shared__ u16 Vts[128 * 64];    // [dim][8 swizzled key-groups of 8]
    __shared__ u16 Pls[4][16 * 72];  // per-wave [q16][64 keys + 8 pad]

    const int tid = threadIdx.x, lane = tid & 63, wave = tid >> 6;
    const int l15 = lane & 15, quad = lane >> 4;
    const int bh = blockIdx.y, b = bh >> 4, h = bh & 15;
    const size_t rowbase = (size_t)b * SQ;
    const int coff = h * 128;
    const float lam = lamp[0];

#pragma unroll 1
    for (int s = 0; s < 2; ++s) {
        const int strip = s ? (31 - (int)blockIdx.x) : (int)blockIdx.x;
        const int q0 = strip * 64;
        const int nt = strip + 1;

        // Q fragments (A layout: m=lane&15, k=quad*8+j), persistent per strip
        bf16x8 qf[2][2];
        {
            const size_t qbase = (rowbase + q0 + wave * 16 + l15) * DMODEL + coff + quad * 8;
#pragma unroll
            for (int hf = 0; hf < 2; ++hf)
#pragma unroll
                for (int ks = 0; ks < 2; ++ks)
                    qf[hf][ks] = *(const bf16x8*)(qw + qbase + hf * 64 + ks * 32);
        }

        f32x4 O[2][8] = {};
        float mm[2][4], ll[2][4];
#pragma unroll
        for (int hf = 0; hf < 2; ++hf)
#pragma unroll
            for (int r = 0; r < 4; ++r) { mm[hf][r] = -1e30f; ll[hf][r] = 0.f; }

        for (int t = 0; t < nt; ++t) {
            const int t0 = t * 64;
            __syncthreads();
            // stage K and V^T tiles (xor-swizzled)
#pragma unroll
            for (int it = 0; it < 4; ++it) {
                const int slot = it * 256 + tid;
                {
                    const int key = slot >> 4, cg = slot & 15;
                    const int cgp = cg ^ (key & 7);
                    *(uint4*)&Ks[key * 128 + cgp * 8] =
                        *(const uint4*)(kw + (rowbase + t0 + key) * DMODEL + coff + cg * 8);
                }
                {
                    const int d = slot >> 3, kg = slot & 7;
                    const int kgp = kg ^ (d & 7);
                    *(uint4*)&Vts[d * 64 + kgp * 8] =
                        *(const uint4*)(vtg + ((size_t)bh * 128 + d) * SQ + t0 + kg * 8);
                }
            }
            __syncthreads();
            const bool maskt = (t == nt - 1);   // only diagonal tile needs masking

#pragma unroll
            for (int hf = 0; hf < 2; ++hf) {
                // ---- S = Q_hf K_hf^T (16 q x 64 keys per wave) ----
                f32x4 S[4] = {};
#pragma unroll
                for (int nb = 0; nb < 4; ++nb)
#pragma unroll
                    for (int ks = 0; ks < 2; ++ks) {
                        const int cgp = (hf * 8 + ks * 4 + quad) ^ (l15 & 7);
                        bf16x8 kf = *(const bf16x8*)&Ks[(nb * 16 + l15) * 128 + cgp * 8];
                        S[nb] = __builtin_amdgcn_mfma_f32_16x16x32_bf16(qf[hf][ks], kf, S[nb], 0, 0, 0);
                    }
                // ---- scale + causal mask + row max ----
                float mt[4];
#pragma unroll
                for (int r = 0; r < 4; ++r) mt[r] = -1e30f;
#pragma unroll
                for (int nb = 0; nb < 4; ++nb)
#pragma unroll
                    for (int r = 0; r < 4; ++r) {
                        float sv = S[nb][r] * 0.125f;
                        if (maskt && (nb * 16 + l15 > wave * 16 + quad * 4 + r)) sv = -1e30f;
                        S[nb][r] = sv;
                        mt[r] = fmaxf(mt[r], sv);
                    }
#pragma unroll
                for (int r = 0; r < 4; ++r)
#pragma unroll
                    for (int off = 1; off < 16; off <<= 1)
                        mt[r] = fmaxf(mt[r], __shfl_xor(mt[r], off));
                // ---- online softmax update ----
                float alpha[4], ps[4];
#pragma unroll
                for (int r = 0; r < 4; ++r) {
                    const float mn = fmaxf(mm[hf][r], mt[r]);
                    alpha[r] = __expf(mm[hf][r] - mn);
                    mm[hf][r] = mn;
                    ps[r] = 0.f;
                }
#pragma unroll
                for (int nb = 0; nb < 4; ++nb)
#pragma unroll
                    for (int r = 0; r < 4; ++r) {
                        const float p = __expf(S[nb][r] - mm[hf][r]);
                        const u16 pq = f2bf(p);
                        ps[r] += bf2f(pq);    // sum quantized p for consistent normalization
                        Pls[wave][(quad * 4 + r) * 72 + nb * 16 + l15] = pq;
                    }
#pragma unroll
                for (int r = 0; r < 4; ++r) {
#pragma unroll
                    for (int off = 1; off < 16; off <<= 1) ps[r] += __shfl_xor(ps[r], off);
                    ll[hf][r] = ll[hf][r] * alpha[r] + ps[r];
                }
                // ---- rescale O, then O += P V ----
#pragma unroll
                for (int nb = 0; nb < 8; ++nb)
#pragma unroll
                    for (int r = 0; r < 4; ++r) O[hf][nb][r] *= alpha[r];
                bf16x8 pf[2];
#pragma unroll
                for (int ks = 0; ks < 2; ++ks)
                    pf[ks] = *(const bf16x8*)&Pls[wave][l15 * 72 + ks * 32 + quad * 8];
#pragma unroll
                for (int nb = 0; nb < 8; ++nb)
#pragma unroll
                    for (int ks = 0; ks < 2; ++ks) {
                        const int kgp = (ks * 4 + quad) ^ (l15 & 7);
                        bf16x8 vf = *(const bf16x8*)&Vts[(nb * 16 + l15) * 64 + kgp * 8];
                        O[hf][nb] = __builtin_amdgcn_mfma_f32_16x16x32_bf16(pf[ks], vf, O[hf][nb], 0, 0, 0);
                    }
            }
        }

        // ---- epilogue: y = rmsnorm(O1/l1 - lam*O2/l2) * w + b, * OUT_SCALE ----
        float inl1[4], inl2[4];
#pragma unroll
        for (int r = 0; r < 4; ++r) { inl1[r] = 1.f / ll[0][r]; inl2[r] = 1.f / ll[1][r]; }
        float vv[8][4], ss[4] = {0.f, 0.f, 0.f, 0.f};
#pragma unroll
        for (int nb = 0; nb < 8; ++nb)
#pragma unroll
            for (int r = 0; r < 4; ++r) {
                const float v = O[0][nb][r] * inl1[r] - lam * O[1][nb][r] * inl2[r];
                vv[nb][r] = v;
                ss[r] += v * v;
            }
#pragma unroll
        for (int r = 0; r < 4; ++r) {
#pragma unroll
            for (int off = 1; off < 16; off <<= 1) ss[r] += __shfl_xor(ss[r], off);
            ss[r] = rsqrtf(ss[r] * (1.f / 128.f) + 1e-8f) * OUT_SCALE;
        }
#pragma unroll
        for (int nb = 0; nb < 8; ++nb) {
            const int d = nb * 16 + l15;
            const float w = lnw[d], bb = lnb[d] * OUT_SCALE;
#pragma unroll
            for (int r = 0; r < 4; ++r) {
                const size_t row = rowbase + q0 + wave * 16 + quad * 4 + r;
                yb[row * DMODEL + coff + d] = f2bf(vv[nb][r] * ss[r] * w + bb);
            }
        }
    }
}

// ---------- workspace layout (bytes) ----------
#define WT_OFF   0ull                 // 4 x 2048x2048 bf16 = 32 MB
#define XB_OFF   33554432ull          // 4096x2048 bf16 (xb, reused as yb)
#define Q_OFF    50331648ull          // 4096x2048 bf16
#define K_OFF    67108864ull
#define V_OFF    83886080ull
#define VT_OFF   100663296ull         // 32 bh x 128 x 2048 bf16 = 16 MB
#define LAM_OFF  117440512ull
#define WS_NEED  117440768ull

extern "C" void kernel_launch(void* const* d_in, const int* in_sizes, int n_in,
                              void* d_out, int out_size, void* d_ws, size_t ws_size,
                              hipStream_t stream) {
    if (ws_size < WS_NEED) return;
    const float* x   = (const float*)d_in[0];
    const float* Wq  = (const float*)d_in[1];
    const float* Wk  = (const float*)d_in[2];
    const float* Wv  = (const float*)d_in[3];
    const float* Wo  = (const float*)d_in[4];
    const float* lq1 = (const float*)d_in[5];
    const float* lk1 = (const float*)d_in[6];
    const float* lq2 = (const float*)d_in[7];
    const float* lk2 = (const float*)d_in[8];
    const float* lnw = (const float*)d_in[9];
    const float* lnb = (const float*)d_in[10];

    char* ws = (char*)d_ws;
    u16* wt  = (u16*)(ws + WT_OFF);
    u16* xb  = (u16*)(ws + XB_OFF);   // also yb after attention
    u16* qb  = (u16*)(ws + Q_OFF);
    u16* kb  = (u16*)(ws + K_OFF);
    u16* vb  = (u16*)(ws + V_OFF);
    u16* vtg = (u16*)(ws + VT_OFF);
    float* lam = (float*)(ws + LAM_OFF);
    float* out = (float*)d_out;

    // 1. transpose + convert weights
    transpose_w<<<dim3(64, 64, 4), dim3(32, 8, 1), 0, stream>>>(Wq, Wk, Wv, Wo, wt);
    // 2. x -> bf16
    cvt_x<<<dim3(4096), dim3(256), 0, stream>>>(x, xb);
    // 3. q,k,v GEMMs (bf16 out)
    gemm_bt<true><<<dim3(16, 32, 3), dim3(256), 0, stream>>>(xb, wt, qb);
    // 4. RoPE in place on q and k
    rope_kernel<<<dim3(4096, 2), dim3(256), 0, stream>>>(qb, kb);
    // 5. lambda
    lam_kernel<<<dim3(1), dim3(64), 0, stream>>>(lq1, lk1, lq2, lk2, lam);
    // 6. V transpose for PV MFMA B-operand
    vtrans<<<dim3(32, 2, 32), dim3(256), 0, stream>>>(vb, vtg);
    // 7. MFMA flash attention (balanced pairing) + fused combine/RMSNorm -> yb
    attn_kernel<<<dim3(16, 32), dim3(256), 0, stream>>>(qb, kb, vtg, lam, lnw, lnb, xb);
    // 8. out = y @ Wo  (f32 out)
    gemm_bt<false><<<dim3(16, 32, 1), dim3(256), 0, stream>>>(xb, wt + 3ull * DMODEL * DMODEL, out);
}